// Round 3
// baseline (254.392 us; speedup 1.0000x reference)
//
#include <hip/hip_runtime.h>

#define Bb 8
#define Cc 64
#define Hh 200
#define Ww 320
#define Nn 48
#define WDd 80
#define HW (Hh*Ww)      // 64000
#define U2 (HW/2)       // 32000 float2 units per (b,c) plane

typedef float vfloat2 __attribute__((ext_vector_type(2)));

// ---------------------------------------------------------------------------
// Kernel 1: per (b,n) block of 256 threads (unchanged from round 2, ~3 µs).
//   phase A: mean over WD of kernel_feats[b,:,idx,:]  (float4, 4-way split)
//   phase B: vk = Wk·kfm + bk
//   phase C: WeffT[b][c'][n] = vk·Wf[:,c'] ; beff = vk·bf + vk[64]; centers
// ---------------------------------------------------------------------------
__global__ __launch_bounds__(256) void prep_kernel(
    const float* __restrict__ kf, const float* __restrict__ Wk,
    const float* __restrict__ bk, const float* __restrict__ Wf,
    const float* __restrict__ bf, const float* __restrict__ db,
    const int* __restrict__ pad_w,
    float* __restrict__ weffT, float* __restrict__ beff,
    float* __restrict__ centers)
{
    const int n = blockIdx.x, b = blockIdx.y, tid = threadIdx.x;
    const int c = tid & 63, q = tid >> 6;
    const float stride = (float)pad_w[0] / (float)Ww;   // 4.0
    const float yc = (db[(b*Nn + n)*4 + 1] + db[(b*Nn + n)*4 + 3]) / (2.0f * stride);
    const int idx = (int)yc;

    __shared__ float part[Cc][5];
    __shared__ float kfm[Cc];
    __shared__ float vk[Cc + 1];

    {
        const float4* row = (const float4*)(kf + ((size_t)(b*Cc + c)*Hh + idx)*WDd) + q*5;
        float4 v0 = row[0], v1 = row[1], v2 = row[2], v3 = row[3], v4 = row[4];
        float s = (v0.x+v0.y+v0.z+v0.w) + (v1.x+v1.y+v1.z+v1.w)
                + (v2.x+v2.y+v2.z+v2.w) + (v3.x+v3.y+v3.z+v3.w)
                + (v4.x+v4.y+v4.z+v4.w);
        part[c][q] = s;
    }
    __syncthreads();
    if (tid < Cc)
        kfm[tid] = (part[tid][0]+part[tid][1]+part[tid][2]+part[tid][3]) * (1.0f/(float)WDd);
    __syncthreads();

    if (tid < Cc + 1) {
        float a = bk[tid];
        const float4* wr = (const float4*)(Wk + tid*Cc);
        #pragma unroll
        for (int i = 0; i < 16; ++i) {
            float4 wv = wr[i];
            a = fmaf(wv.x, kfm[4*i+0], a);
            a = fmaf(wv.y, kfm[4*i+1], a);
            a = fmaf(wv.z, kfm[4*i+2], a);
            a = fmaf(wv.w, kfm[4*i+3], a);
        }
        vk[tid] = a;
    }
    __syncthreads();

    if (tid < Cc) {
        float wsum = 0.f;
        #pragma unroll 8
        for (int c2 = 0; c2 < Cc; ++c2) wsum = fmaf(vk[c2], Wf[c2*Cc + tid], wsum);
        weffT[((size_t)b*Cc + tid)*Nn + n] = wsum;
    } else if (tid == Cc) {
        float bb2 = vk[Cc];
        #pragma unroll 8
        for (int c2 = 0; c2 < Cc; ++c2) bb2 = fmaf(vk[c2], bf[c2], bb2);
        beff[b*Nn + n] = bb2;
        centers[b*Nn + n] = yc * stride;
    }
}

// ---------------------------------------------------------------------------
// Kernel 2: logits[b,n,h,w] = sum_c WeffT[b][c][n]*feats[b,c,h,w] + beff[b,n]
// Flattened H*W plane in float2 units: 500 FULL waves per b (no idle lanes;
// a float2 never crosses a row since 320%4==0). Nontemporal loads/stores for
// the two pure streams. Ballot keeps the masked-wave skip wave-uniform.
// ---------------------------------------------------------------------------
__global__ __launch_bounds__(256) void logits_kernel(
    const float* __restrict__ feats, const int* __restrict__ ishape,
    const int* __restrict__ pad_w, const float* __restrict__ weffT,
    const float* __restrict__ beff, float* __restrict__ out)
{
    const int b = blockIdx.y;
    const int u = blockIdx.x * 256 + threadIdx.x;   // float2 unit, [0, 32000)
    const int h  = u / (Ww/2);
    const int w0 = (u - h*(Ww/2)) * 2;

    const float stride = (float)pad_w[0] / (float)Ww;
    const int hlim = (int)((float)ishape[b*2 + 1] / stride);
    const int wlim = (int)((float)ishape[b*2 + 0] / stride);
    const bool act0 = (h < hlim) && (w0     < wlim);   // act1 => act0
    const bool act1 = (h < hlim) && (w0 + 1 < wlim);

    vfloat2 acc[Nn];
    if (__ballot(act0) != 0ULL) {                      // wave-uniform branch
        const float* __restrict__ bv = beff + b*Nn;
        #pragma unroll
        for (int n = 0; n < Nn; ++n) { acc[n][0] = bv[n]; acc[n][1] = bv[n]; }

        const float* __restrict__ fp = feats + (size_t)b*Cc*HW + 2*u;
        const float* __restrict__ wT = weffT + (size_t)b*Cc*Nn;
        #pragma unroll 4
        for (int c = 0; c < Cc; ++c) {
            const vfloat2 fv = __builtin_nontemporal_load(
                (const vfloat2*)(fp + (size_t)c * HW));
            const float* __restrict__ wrow = wT + c*Nn;
            #pragma unroll
            for (int n = 0; n < Nn; ++n) {
                acc[n][0] = fmaf(wrow[n], fv[0], acc[n][0]);
                acc[n][1] = fmaf(wrow[n], fv[1], acc[n][1]);
            }
        }
        #pragma unroll
        for (int n = 0; n < Nn; ++n) {
            acc[n][0] = act0 ? acc[n][0] : -1e8f;
            acc[n][1] = act1 ? acc[n][1] : -1e8f;
        }
    } else {
        #pragma unroll
        for (int n = 0; n < Nn; ++n) { acc[n][0] = -1e8f; acc[n][1] = -1e8f; }
    }

    float* op = out + (size_t)b*Nn*HW + 2*u;
    #pragma unroll
    for (int n = 0; n < Nn; ++n)
        __builtin_nontemporal_store(acc[n], (vfloat2*)(op + (size_t)n * HW));
}

extern "C" void kernel_launch(void* const* d_in, const int* in_sizes, int n_in,
                              void* d_out, int out_size, void* d_ws, size_t ws_size,
                              hipStream_t stream) {
    const float* feats  = (const float*)d_in[0];
    const float* kf     = (const float*)d_in[1];
    const float* Wk     = (const float*)d_in[2];
    const float* bk     = (const float*)d_in[3];
    const float* Wf     = (const float*)d_in[4];
    const float* bf     = (const float*)d_in[5];
    const float* db     = (const float*)d_in[6];
    const int*   ishape = (const int*)d_in[7];
    const int*   pad_w  = (const int*)d_in[8];

    float* out    = (float*)d_out;
    float* weffT  = (float*)d_ws;                      // B*64*48 floats
    float* beff   = weffT + (size_t)Bb*Cc*Nn;          // B*48 floats
    float* centers = out + (size_t)Bb*Nn*Hh*Ww;        // second output

    prep_kernel<<<dim3(Nn, Bb), 256, 0, stream>>>(
        kf, Wk, bk, Wf, bf, db, pad_w, weffT, beff, centers);

    logits_kernel<<<dim3(U2/256, Bb), 256, 0, stream>>>(
        feats, ishape, pad_w, weffT, beff, out);
}